// Round 5
// baseline (326.825 us; speedup 1.0000x reference)
//
#include <hip/hip_runtime.h>

// GCN 3-layer, R5.
//  a1 = S x  (float4 {Sx.xyz, dinv^2}), 16-lane-group per node.
//  fused_l2l3: wave-per-node, lane=feature. Streams ew + a1[s] gathers 8-deep,
//              recomputes h1 per edge in-reg, a2 via LDS exchange, W2 column
//              REGISTER-resident (launch_bounds forces budget), z scalar out.
//  logits = S z + c, 16-lane-group per node.
// ws floats: dinv[N] | a1[4N] | rowptr[N+1] | bsums[1024] | ew[2E] | z[N] | wc[65] | cnt[N]|fill[N]

__global__ void count_deg(const int* __restrict__ dst, int* __restrict__ cnt, int E) {
    int e = blockIdx.x * blockDim.x + threadIdx.x;
    if (e < E) atomicAdd(&cnt[dst[e]], 1);
}

// exclusive scan phase 1 (+ dinv fused: v = deg, dinv = rsqrt(deg+1))
__global__ void scan1(const int* __restrict__ cnt, int* __restrict__ rowptr,
                      int* __restrict__ bsums, float* __restrict__ dinv, int N) {
    __shared__ int tmp[256];
    int i = blockIdx.x * 256 + threadIdx.x;
    int v = (i < N) ? cnt[i] : 0;
    if (i < N) dinv[i] = rsqrtf((float)(v + 1));
    tmp[threadIdx.x] = v; __syncthreads();
    for (int off = 1; off < 256; off <<= 1) {
        int t = (threadIdx.x >= off) ? tmp[threadIdx.x - off] : 0;
        __syncthreads();
        tmp[threadIdx.x] += t;
        __syncthreads();
    }
    if (i < N) rowptr[i] = tmp[threadIdx.x] - v;
    if (threadIdx.x == 255) bsums[blockIdx.x] = tmp[255];
}

__global__ void scan2(int* __restrict__ bsums, int nb) {    // 1 block, 1024 thr
    __shared__ int tmp[1024];
    int v = (threadIdx.x < nb) ? bsums[threadIdx.x] : 0;
    tmp[threadIdx.x] = v; __syncthreads();
    for (int off = 1; off < 1024; off <<= 1) {
        int t = (threadIdx.x >= off) ? tmp[threadIdx.x - off] : 0;
        __syncthreads();
        tmp[threadIdx.x] += t;
        __syncthreads();
    }
    if (threadIdx.x < nb) bsums[threadIdx.x] = tmp[threadIdx.x] - v;
}

__global__ void scan3(int* __restrict__ rowptr, const int* __restrict__ bsums, int N, int E) {
    int i = blockIdx.x * 256 + threadIdx.x;
    if (i < N) rowptr[i] += bsums[blockIdx.x];
    if (i == 0) rowptr[N] = E;
}

__global__ void csr_fill(const int* __restrict__ src, const int* __restrict__ dst,
                         const float* __restrict__ dinv, const int* __restrict__ rowptr,
                         int* __restrict__ fill, float2* __restrict__ ew, int E) {
    int e = blockIdx.x * blockDim.x + threadIdx.x;
    if (e >= E) return;
    int s = src[e], d = dst[e];
    int p = rowptr[d] + atomicAdd(&fill[d], 1);
    ew[p] = make_float2(__int_as_float(s), dinv[s] * dinv[d]);
}

// a1[n] = {S x}[n], .w = dinv^2; 16-lane group per node
__global__ void agg3_wave(const float* __restrict__ x, const float2* __restrict__ ew,
                          const int* __restrict__ rowptr, const float* __restrict__ dinv,
                          float4* __restrict__ a1, int N) {
    int g   = (blockIdx.x * blockDim.x + threadIdx.x) >> 4;
    int sub = threadIdx.x & 15;
    if (g >= N) return;
    int p0 = rowptr[g], p1 = rowptr[g+1];
    float ax = 0.f, ay = 0.f, az = 0.f;
    for (int p = p0 + sub; p < p1; p += 16) {
        float2 e = ew[p];
        int s = __float_as_int(e.x);
        ax = fmaf(e.y, x[s*3+0], ax);
        ay = fmaf(e.y, x[s*3+1], ay);
        az = fmaf(e.y, x[s*3+2], az);
    }
    #pragma unroll
    for (int off = 8; off; off >>= 1) {
        ax += __shfl_down(ax, off, 16);
        ay += __shfl_down(ay, off, 16);
        az += __shfl_down(az, off, 16);
    }
    if (sub == 0) {
        float dv = dinv[g], sw = dv * dv;
        a1[g] = make_float4(fmaf(sw, x[g*3+0], ax),
                            fmaf(sw, x[g*3+1], ay),
                            fmaf(sw, x[g*3+2], az), sw);
    }
}

// wc[k] = W3[k][:] @ Wh; wc[64] = b3 @ Wh + bh
__global__ void fold_head(const float* __restrict__ W3, const float* __restrict__ b3,
                          const float* __restrict__ Wh, const float* __restrict__ bh,
                          float* __restrict__ wc) {
    int k = threadIdx.x;              // 64
    float acc = 0.0f;
    for (int f = 0; f < 64; f++) acc += W3[k*64+f] * Wh[f];
    wc[k] = acc;
    if (k == 0) {
        float bb = bh[0];
        for (int f = 0; f < 64; f++) bb += b3[f] * Wh[f];
        wc[64] = bb;
    }
}

// z[n] = relu( (S relu(a1@W1+b1))[n] @ W2 + b2 ) @ wc
__global__ __launch_bounds__(256, 2)
void fused_l2l3(const float2* __restrict__ ew, const int* __restrict__ rowptr,
                const float4* __restrict__ a1, const float* __restrict__ W1,
                const float* __restrict__ b1, const float* __restrict__ W2,
                const float* __restrict__ b2, const float* __restrict__ wc,
                float* __restrict__ z, int N) {
    __shared__ float a2buf[4][64];
    const int lane = threadIdx.x & 63;
    const int wv   = threadIdx.x >> 6;
    const float w10 = W1[lane], w11 = W1[64 + lane], w12 = W1[128 + lane];
    const float b1f = b1[lane], b2f = b2[lane], wcf = wc[lane];
    float w2col[64];                                   // register-resident W2 column
    #pragma unroll
    for (int k = 0; k < 64; ++k) w2col[k] = W2[k*64 + lane];
    const int NPW = 8;
    int n0 = (blockIdx.x * 4 + wv) * NPW;
    for (int i = 0; i < NPW; ++i) {
        int n = n0 + i;                                // wave-uniform
        if (n >= N) break;
        float4 an = a1[n];
        float ts = fmaf(an.z, w12, fmaf(an.y, w11, fmaf(an.x, w10, b1f)));
        float acc0 = an.w * fmaxf(ts, 0.f), acc1 = 0.f;
        int p = rowptr[n], pe = rowptr[n+1];
        for (; p + 7 < pe; p += 8) {                   // 8 chains in flight
            float2 e0 = ew[p+0], e1 = ew[p+1], e2 = ew[p+2], e3 = ew[p+3];
            float2 e4 = ew[p+4], e5 = ew[p+5], e6 = ew[p+6], e7 = ew[p+7];
            float4 s0 = a1[__float_as_int(e0.x)], s1 = a1[__float_as_int(e1.x)];
            float4 s2 = a1[__float_as_int(e2.x)], s3 = a1[__float_as_int(e3.x)];
            float4 s4 = a1[__float_as_int(e4.x)], s5 = a1[__float_as_int(e5.x)];
            float4 s6 = a1[__float_as_int(e6.x)], s7 = a1[__float_as_int(e7.x)];
            float t0 = fmaf(s0.z, w12, fmaf(s0.y, w11, fmaf(s0.x, w10, b1f)));
            float t1 = fmaf(s1.z, w12, fmaf(s1.y, w11, fmaf(s1.x, w10, b1f)));
            float t2 = fmaf(s2.z, w12, fmaf(s2.y, w11, fmaf(s2.x, w10, b1f)));
            float t3 = fmaf(s3.z, w12, fmaf(s3.y, w11, fmaf(s3.x, w10, b1f)));
            float t4 = fmaf(s4.z, w12, fmaf(s4.y, w11, fmaf(s4.x, w10, b1f)));
            float t5 = fmaf(s5.z, w12, fmaf(s5.y, w11, fmaf(s5.x, w10, b1f)));
            float t6 = fmaf(s6.z, w12, fmaf(s6.y, w11, fmaf(s6.x, w10, b1f)));
            float t7 = fmaf(s7.z, w12, fmaf(s7.y, w11, fmaf(s7.x, w10, b1f)));
            acc0 = fmaf(e0.y, fmaxf(t0, 0.f), acc0);
            acc1 = fmaf(e1.y, fmaxf(t1, 0.f), acc1);
            acc0 = fmaf(e2.y, fmaxf(t2, 0.f), acc0);
            acc1 = fmaf(e3.y, fmaxf(t3, 0.f), acc1);
            acc0 = fmaf(e4.y, fmaxf(t4, 0.f), acc0);
            acc1 = fmaf(e5.y, fmaxf(t5, 0.f), acc1);
            acc0 = fmaf(e6.y, fmaxf(t6, 0.f), acc0);
            acc1 = fmaf(e7.y, fmaxf(t7, 0.f), acc1);
        }
        for (; p < pe; ++p) {
            float2 e = ew[p];
            float4 s = a1[__float_as_int(e.x)];
            float tt = fmaf(s.z, w12, fmaf(s.y, w11, fmaf(s.x, w10, b1f)));
            acc0 = fmaf(e.y, fmaxf(tt, 0.f), acc0);
        }
        // a2 exchange (wave-private LDS row; in-order within wave)
        a2buf[wv][lane] = acc0 + acc1;
        float h0 = b2f, h1 = 0.f, h2 = 0.f, h3 = 0.f;
        const float4* a4 = (const float4*)a2buf[wv];
        #pragma unroll
        for (int k4 = 0; k4 < 16; ++k4) {
            float4 a = a4[k4];                         // wave-uniform broadcast
            h0 = fmaf(a.x, w2col[4*k4+0], h0);
            h1 = fmaf(a.y, w2col[4*k4+1], h1);
            h2 = fmaf(a.z, w2col[4*k4+2], h2);
            h3 = fmaf(a.w, w2col[4*k4+3], h3);
        }
        float v = fmaxf((h0 + h1) + (h2 + h3), 0.f) * wcf;
        #pragma unroll
        for (int off = 32; off; off >>= 1) v += __shfl_down(v, off);
        if (lane == 0) z[n] = v;
    }
}

// logits[n] = dinv^2 z[n] + sum_e w z[s] + c; 16-lane group per node
__global__ void final_wave(const float* __restrict__ z, const float2* __restrict__ ew,
                           const int* __restrict__ rowptr, const float* __restrict__ dinv,
                           const float* __restrict__ wc, float* __restrict__ out, int N) {
    int g   = (blockIdx.x * blockDim.x + threadIdx.x) >> 4;
    int sub = threadIdx.x & 15;
    if (g >= N) return;
    int p0 = rowptr[g], p1 = rowptr[g+1];
    float acc = 0.f;
    for (int p = p0 + sub; p < p1; p += 16) {
        float2 e = ew[p];
        acc = fmaf(e.y, z[__float_as_int(e.x)], acc);
    }
    #pragma unroll
    for (int off = 8; off; off >>= 1) acc += __shfl_down(acc, off, 16);
    if (sub == 0) {
        float dv = dinv[g];
        out[g] = fmaf(dv * dv, z[g], acc) + wc[64];
    }
}

extern "C" void kernel_launch(void* const* d_in, const int* in_sizes, int n_in,
                              void* d_out, int out_size, void* d_ws, size_t ws_size,
                              hipStream_t stream) {
    const float* x   = (const float*)d_in[0];
    const int*   ei  = (const int*)d_in[1];
    const float* W1  = (const float*)d_in[2];
    const float* b1  = (const float*)d_in[3];
    const float* W2  = (const float*)d_in[4];
    const float* b2  = (const float*)d_in[5];
    const float* W3  = (const float*)d_in[6];
    const float* b3  = (const float*)d_in[7];
    const float* Wh  = (const float*)d_in[8];
    const float* bh  = (const float*)d_in[9];
    float* logits = (float*)d_out;

    const int N = in_sizes[0] / 3;
    const int E = in_sizes[1] / 2;
    const int* src = ei;
    const int* dst = ei + E;

    float* base = (float*)d_ws;
    size_t o = 0;
    float*  dinv   = base + o; o += (size_t)N;
    o = (o + 3) & ~(size_t)3;
    float4* a1     = (float4*)(base + o); o += (size_t)4*N;
    int*    rowptr = (int*)(base + o); o += (size_t)N + 1;
    int*    bsums  = (int*)(base + o); o += 1024;
    o = (o + 1) & ~(size_t)1;
    float2* ew     = (float2*)(base + o); o += (size_t)2*E;
    float*  zbuf   = base + o; o += (size_t)N;
    float*  wc     = base + o; o += 65;
    int*    cnt    = (int*)(base + o); o += (size_t)N;   // cnt|fill contiguous
    int*    fill   = (int*)(base + o); o += (size_t)N;

    const int BS = 256;
    int gE  = (E + BS - 1) / BS;
    int gN  = (N + BS - 1) / BS;
    int g16 = ((size_t)N * 16 + BS - 1) / BS;   // 16-lane group per node
    int gFU = (N + 31) / 32;                    // 4 waves x 8 nodes per block

    hipMemsetAsync(cnt, 0, (size_t)2 * N * sizeof(int), stream);

    count_deg   <<<gE, BS, 0, stream>>>(dst, cnt, E);
    scan1       <<<gN, BS, 0, stream>>>(cnt, rowptr, bsums, dinv, N);
    scan2       <<<1, 1024, 0, stream>>>(bsums, gN);
    scan3       <<<gN, BS, 0, stream>>>(rowptr, bsums, N, E);
    csr_fill    <<<gE, BS, 0, stream>>>(src, dst, dinv, rowptr, fill, ew, E);

    agg3_wave   <<<g16, BS, 0, stream>>>(x, ew, rowptr, dinv, a1, N);
    fold_head   <<<1, 64, 0, stream>>>(W3, b3, Wh, bh, wc);
    fused_l2l3  <<<gFU, BS, 0, stream>>>(ew, rowptr, a1, W1, b1, W2, b2, wc, zbuf, N);
    final_wave  <<<g16, BS, 0, stream>>>(zbuf, ew, rowptr, dinv, wc, logits, N);
}

// Round 6
// 252.693 us; speedup vs baseline: 1.2934x; 1.2934x over previous
//
#include <hip/hip_runtime.h>

// GCN 3-layer, R6: fused kernel rebuilt around per-lane loads + readlane broadcast.
//  a1 = S x  (float4 {Sx.xyz, dinv^2}), 16-lane-group per node.
//  fused_l2l3: wave per 8 nodes, lane=feature. Per node: ONE coalesced ew load
//    (lane=edge) + ONE per-lane a1[src] gather (64-wide MLP), then v_readlane
//    broadcast per edge -> h1 recompute in-reg -> a2 -> LDS W2 matmul -> z.
//  logits = S z + c, 16-lane-group per node.
// ws floats: dinv[N] | a1[4N] | rowptr[N+1] | bsums[1024] | ew[2E] | z[N] | wc[65] | cnt[N]|fill[N]

__device__ __forceinline__ float rlane(float v, int l) {
    return __int_as_float(__builtin_amdgcn_readlane(__float_as_int(v), l));
}

__global__ void count_deg(const int* __restrict__ dst, int* __restrict__ cnt, int E) {
    int e = blockIdx.x * blockDim.x + threadIdx.x;
    if (e < E) atomicAdd(&cnt[dst[e]], 1);
}

// exclusive scan phase 1 (+ dinv fused)
__global__ void scan1(const int* __restrict__ cnt, int* __restrict__ rowptr,
                      int* __restrict__ bsums, float* __restrict__ dinv, int N) {
    __shared__ int tmp[256];
    int i = blockIdx.x * 256 + threadIdx.x;
    int v = (i < N) ? cnt[i] : 0;
    if (i < N) dinv[i] = rsqrtf((float)(v + 1));
    tmp[threadIdx.x] = v; __syncthreads();
    for (int off = 1; off < 256; off <<= 1) {
        int t = (threadIdx.x >= off) ? tmp[threadIdx.x - off] : 0;
        __syncthreads();
        tmp[threadIdx.x] += t;
        __syncthreads();
    }
    if (i < N) rowptr[i] = tmp[threadIdx.x] - v;
    if (threadIdx.x == 255) bsums[blockIdx.x] = tmp[255];
}

__global__ void scan2(int* __restrict__ bsums, int nb) {    // 1 block, 1024 thr
    __shared__ int tmp[1024];
    int v = (threadIdx.x < nb) ? bsums[threadIdx.x] : 0;
    tmp[threadIdx.x] = v; __syncthreads();
    for (int off = 1; off < 1024; off <<= 1) {
        int t = (threadIdx.x >= off) ? tmp[threadIdx.x - off] : 0;
        __syncthreads();
        tmp[threadIdx.x] += t;
        __syncthreads();
    }
    if (threadIdx.x < nb) bsums[threadIdx.x] = tmp[threadIdx.x] - v;
}

__global__ void scan3(int* __restrict__ rowptr, const int* __restrict__ bsums, int N, int E) {
    int i = blockIdx.x * 256 + threadIdx.x;
    if (i < N) rowptr[i] += bsums[blockIdx.x];
    if (i == 0) rowptr[N] = E;
}

__global__ void csr_fill(const int* __restrict__ src, const int* __restrict__ dst,
                         const float* __restrict__ dinv, const int* __restrict__ rowptr,
                         int* __restrict__ fill, float2* __restrict__ ew, int E) {
    int e = blockIdx.x * blockDim.x + threadIdx.x;
    if (e >= E) return;
    int s = src[e], d = dst[e];
    int p = rowptr[d] + atomicAdd(&fill[d], 1);
    ew[p] = make_float2(__int_as_float(s), dinv[s] * dinv[d]);
}

// a1[n] = {S x}[n], .w = dinv^2; 16-lane group per node
__global__ void agg3_wave(const float* __restrict__ x, const float2* __restrict__ ew,
                          const int* __restrict__ rowptr, const float* __restrict__ dinv,
                          float4* __restrict__ a1, int N) {
    int g   = (blockIdx.x * blockDim.x + threadIdx.x) >> 4;
    int sub = threadIdx.x & 15;
    if (g >= N) return;
    int p0 = rowptr[g], p1 = rowptr[g+1];
    float ax = 0.f, ay = 0.f, az = 0.f;
    for (int p = p0 + sub; p < p1; p += 16) {
        float2 e = ew[p];
        int s = __float_as_int(e.x);
        ax = fmaf(e.y, x[s*3+0], ax);
        ay = fmaf(e.y, x[s*3+1], ay);
        az = fmaf(e.y, x[s*3+2], az);
    }
    #pragma unroll
    for (int off = 8; off; off >>= 1) {
        ax += __shfl_down(ax, off, 16);
        ay += __shfl_down(ay, off, 16);
        az += __shfl_down(az, off, 16);
    }
    if (sub == 0) {
        float dv = dinv[g], sw = dv * dv;
        a1[g] = make_float4(fmaf(sw, x[g*3+0], ax),
                            fmaf(sw, x[g*3+1], ay),
                            fmaf(sw, x[g*3+2], az), sw);
    }
}

// wc[k] = W3[k][:] @ Wh; wc[64] = b3 @ Wh + bh
__global__ void fold_head(const float* __restrict__ W3, const float* __restrict__ b3,
                          const float* __restrict__ Wh, const float* __restrict__ bh,
                          float* __restrict__ wc) {
    int k = threadIdx.x;              // 64
    float acc = 0.0f;
    for (int f = 0; f < 64; f++) acc += W3[k*64+f] * Wh[f];
    wc[k] = acc;
    if (k == 0) {
        float bb = bh[0];
        for (int f = 0; f < 64; f++) bb += b3[f] * Wh[f];
        wc[64] = bb;
    }
}

// z[n] = relu( (S relu(a1@W1+b1))[n] @ W2 + b2 ) @ wc
__global__ void fused_l2l3(const float2* __restrict__ ew, const int* __restrict__ rowptr,
                           const float4* __restrict__ a1, const float* __restrict__ W1,
                           const float* __restrict__ b1, const float* __restrict__ W2,
                           const float* __restrict__ b2, const float* __restrict__ wc,
                           float* __restrict__ z, int N) {
    __shared__ float Wl[64*64];
    __shared__ float a2buf[4][64];
    const int tid = threadIdx.x;
    for (int i = tid; i < 4096; i += 256) Wl[i] = W2[i];
    const int lane = tid & 63;
    const int wv   = tid >> 6;
    const float w10 = W1[lane], w11 = W1[64+lane], w12 = W1[128+lane];
    const float b1f = b1[lane], b2f = b2[lane], wcf = wc[lane];
    const int NPW = 8;
    const int n0 = (blockIdx.x * 4 + wv) * NPW;
    int   rpl = rowptr[min(n0 + lane, N)];         // lanes 0..8 used
    float4 sg = a1[min(n0 + lane, N - 1)];         // lanes 0..7 used (self terms)
    __syncthreads();
    for (int cur = 0; cur < NPW; ++cur) {
        int n = n0 + cur;
        if (n >= N) break;
        int p0 = __builtin_amdgcn_readfirstlane(__shfl(rpl, cur));
        int p1 = __builtin_amdgcn_readfirstlane(__shfl(rpl, cur + 1));
        // self-loop term
        float sx = __shfl(sg.x, cur), sy = __shfl(sg.y, cur);
        float sz = __shfl(sg.z, cur), sw = __shfl(sg.w, cur);
        float t = fmaf(sz, w12, fmaf(sy, w11, fmaf(sx, w10, b1f)));
        float acc = sw * fmaxf(t, 0.f);
        for (int pc = p0; pc < p1; pc += 64) {
            int pidx = pc + lane; if (pidx >= p1) pidx = p1 - 1;   // clamp (valid addr)
            float2 e  = ew[pidx];                  // coalesced per-lane
            float4 g  = a1[__float_as_int(e.x)];   // 64-wide gather: true MLP
            float wgt = e.y;
            int m = p1 - pc; if (m > 64) m = 64;   // uniform (p0,p1 in SGPR)
            #pragma unroll
            for (int j = 0; j < 64; ++j) {
                if (j >= m) break;                 // uniform early exit
                float ex = rlane(g.x, j), ey = rlane(g.y, j);
                float ez = rlane(g.z, j), ww = rlane(wgt, j);
                float tt = fmaf(ez, w12, fmaf(ey, w11, fmaf(ex, w10, b1f)));
                acc = fmaf(ww, fmaxf(tt, 0.f), acc);
            }
        }
        // a2 exchange (wave-private LDS row), then W2 matmul from LDS
        a2buf[wv][lane] = acc;
        float h = b2f;
        const float4* a4 = (const float4*)a2buf[wv];
        #pragma unroll
        for (int k4 = 0; k4 < 16; ++k4) {
            float4 a = a4[k4];                     // uniform broadcast read
            h = fmaf(a.x, Wl[(4*k4+0)*64 + lane], h);
            h = fmaf(a.y, Wl[(4*k4+1)*64 + lane], h);
            h = fmaf(a.z, Wl[(4*k4+2)*64 + lane], h);
            h = fmaf(a.w, Wl[(4*k4+3)*64 + lane], h);
        }
        float v = fmaxf(h, 0.f) * wcf;
        #pragma unroll
        for (int off = 32; off; off >>= 1) v += __shfl_down(v, off);
        if (lane == 0) z[n] = v;
    }
}

// logits[n] = dinv^2 z[n] + sum_e w z[s] + c; 16-lane group per node
__global__ void final_wave(const float* __restrict__ z, const float2* __restrict__ ew,
                           const int* __restrict__ rowptr, const float* __restrict__ dinv,
                           const float* __restrict__ wc, float* __restrict__ out, int N) {
    int g   = (blockIdx.x * blockDim.x + threadIdx.x) >> 4;
    int sub = threadIdx.x & 15;
    if (g >= N) return;
    int p0 = rowptr[g], p1 = rowptr[g+1];
    float acc = 0.f;
    for (int p = p0 + sub; p < p1; p += 16) {
        float2 e = ew[p];
        acc = fmaf(e.y, z[__float_as_int(e.x)], acc);
    }
    #pragma unroll
    for (int off = 8; off; off >>= 1) acc += __shfl_down(acc, off, 16);
    if (sub == 0) {
        float dv = dinv[g];
        out[g] = fmaf(dv * dv, z[g], acc) + wc[64];
    }
}

extern "C" void kernel_launch(void* const* d_in, const int* in_sizes, int n_in,
                              void* d_out, int out_size, void* d_ws, size_t ws_size,
                              hipStream_t stream) {
    const float* x   = (const float*)d_in[0];
    const int*   ei  = (const int*)d_in[1];
    const float* W1  = (const float*)d_in[2];
    const float* b1  = (const float*)d_in[3];
    const float* W2  = (const float*)d_in[4];
    const float* b2  = (const float*)d_in[5];
    const float* W3  = (const float*)d_in[6];
    const float* b3  = (const float*)d_in[7];
    const float* Wh  = (const float*)d_in[8];
    const float* bh  = (const float*)d_in[9];
    float* logits = (float*)d_out;

    const int N = in_sizes[0] / 3;
    const int E = in_sizes[1] / 2;
    const int* src = ei;
    const int* dst = ei + E;

    float* base = (float*)d_ws;
    size_t o = 0;
    float*  dinv   = base + o; o += (size_t)N;
    o = (o + 3) & ~(size_t)3;
    float4* a1     = (float4*)(base + o); o += (size_t)4*N;
    int*    rowptr = (int*)(base + o); o += (size_t)N + 1;
    int*    bsums  = (int*)(base + o); o += 1024;
    o = (o + 1) & ~(size_t)1;
    float2* ew     = (float2*)(base + o); o += (size_t)2*E;
    float*  zbuf   = base + o; o += (size_t)N;
    float*  wc     = base + o; o += 65;
    int*    cnt    = (int*)(base + o); o += (size_t)N;   // cnt|fill contiguous
    int*    fill   = (int*)(base + o); o += (size_t)N;

    const int BS = 256;
    int gE  = (E + BS - 1) / BS;
    int gN  = (N + BS - 1) / BS;
    int g16 = ((size_t)N * 16 + BS - 1) / BS;   // 16-lane group per node
    int gFU = (N + 31) / 32;                    // 4 waves x 8 nodes per block

    hipMemsetAsync(cnt, 0, (size_t)2 * N * sizeof(int), stream);

    count_deg   <<<gE, BS, 0, stream>>>(dst, cnt, E);
    scan1       <<<gN, BS, 0, stream>>>(cnt, rowptr, bsums, dinv, N);
    scan2       <<<1, 1024, 0, stream>>>(bsums, gN);
    scan3       <<<gN, BS, 0, stream>>>(rowptr, bsums, N, E);
    csr_fill    <<<gE, BS, 0, stream>>>(src, dst, dinv, rowptr, fill, ew, E);

    agg3_wave   <<<g16, BS, 0, stream>>>(x, ew, rowptr, dinv, a1, N);
    fold_head   <<<1, 64, 0, stream>>>(W3, b3, Wh, bh, wc);
    fused_l2l3  <<<gFU, BS, 0, stream>>>(ew, rowptr, a1, W1, b1, W2, b2, wc, zbuf, N);
    final_wave  <<<g16, BS, 0, stream>>>(zbuf, ew, rowptr, dinv, wc, logits, N);
}